// Round 2
// baseline (248.152 us; speedup 1.0000x reference)
//
#include <hip/hip_runtime.h>

// LSTM_WP: B=4096 batch-1 LSTMs, T=H=128, input_size=1, fused MFMA-f16 recurrence.
// Round 2: 1024 threads = 16 waves (4/SIMD). Wave pair (w, w+8) computes the SAME
// 16-gate-column tile (redundant MFMA, pipe has headroom) but splits the
// transcendental-heavy elementwise update by accumulator rows: w<8 -> rows {0,1},
// w>=8 -> rows {2,3} of each quad. Halves per-wave trans issue, doubles waves/SIMD
// for MFMA/VALU overlap, keeps ONE barrier per step, no partial-sum exchange.
// xs transposed [T][17] -> conflict-free staging and per-step reads.

#define H   128
#define T   128
#define MB  16          // batches per block
#define BLOCK 1024
#define HSTRIDE 136     // f16 per h row: 272 B (16B aligned)
#define XSTRIDE 17      // floats per xs row (odd -> conflict-free banks)

typedef _Float16 f16x8 __attribute__((ext_vector_type(8)));
typedef float    f32x4 __attribute__((ext_vector_type(4)));

__device__ __forceinline__ float fsig(float v) {
    float e = __expf(-v);
    return __builtin_amdgcn_rcpf(1.0f + e);
}
__device__ __forceinline__ float ftanh(float v) {
    float e = __expf(2.0f * v);
    return 1.0f - 2.0f * __builtin_amdgcn_rcpf(1.0f + e);
}

__launch_bounds__(BLOCK, 4)
__global__ void lstm_fused_kernel(const float* __restrict__ x,
                                  const float* __restrict__ W_ih,
                                  const float* __restrict__ W_hh,
                                  const float* __restrict__ b_ih,
                                  const float* __restrict__ b_hh,
                                  const float* __restrict__ fc_W,
                                  const float* __restrict__ fc_b,
                                  float* __restrict__ out)
{
    __shared__ float xs[T][XSTRIDE];                             // 8.5 KB, transposed
    __shared__ __align__(16) _Float16 hbuf[2][MB][HSTRIDE];      // 8.5 KB h double-buffer

    const int tid   = threadIdx.x;
    const int wave  = tid >> 6;
    const int lane  = tid & 63;
    const int l15   = lane & 15;
    const int q     = lane >> 4;           // 0..3
    const int colw  = wave & 7;            // column tile 0..7
    const int rbase = (wave >> 3) * 2;     // row half: 0 or 2
    const int jcol  = colw * 16 + l15;     // this lane's hidden column, 0..127

    // ---- stage x: global batch-major -> LDS [t][b], coalesced reads, odd-stride banks ----
    {
        const int t0 = tid & 127;
        const int b0 = tid >> 7;           // 0..7
        const float* xb = x + (size_t)blockIdx.x * (MB * T);
        xs[t0][b0]     = xb[b0 * T + t0];
        xs[t0][b0 + 8] = xb[(b0 + 8) * T + t0];
    }
    // zero the t=0 read buffer (h0 = 0)
    for (int i = tid; i < MB * HSTRIDE; i += BLOCK)
        (&hbuf[0][0][0])[i] = (_Float16)0.0f;

    // ---- preload W_hh B-fragments + (W_ih, b_ih+b_hh) for this lane's 4 gate rows ----
    f16x8 wf[4][4];            // [gate][k chunk]
    float wih[4], bias[4];
    #pragma unroll
    for (int g = 0; g < 4; ++g) {
        const int n = g * H + jcol;
        wih[g]  = W_ih[n];
        bias[g] = b_ih[n] + b_hh[n];
        #pragma unroll
        for (int kc = 0; kc < 4; ++kc) {
            const float* wp = W_hh + (size_t)n * H + kc * 32 + q * 8;
            float4 w0 = ((const float4*)wp)[0];
            float4 w1 = ((const float4*)wp)[1];
            f16x8 f;
            f[0] = (_Float16)w0.x; f[1] = (_Float16)w0.y;
            f[2] = (_Float16)w0.z; f[3] = (_Float16)w0.w;
            f[4] = (_Float16)w1.x; f[5] = (_Float16)w1.y;
            f[6] = (_Float16)w1.z; f[7] = (_Float16)w1.w;
            wf[g][kc] = f;
        }
    }

    float c0 = 0.f, c1 = 0.f;              // cell state for this wave's 2 rows

    __syncthreads();

    for (int t = 0; t < T; ++t) {
        const int rb = t & 1;
        const int wb = rb ^ 1;

        // A-fragments: m(batch)=lane&15, k = kc*32 + q*8 + i
        f16x8 af[4];
        #pragma unroll
        for (int kc = 0; kc < 4; ++kc)
            af[kc] = *(const f16x8*)&hbuf[rb][l15][kc * 32 + q * 8];

        // acc init = gate pre-activations (all 4 rows needed as MFMA C input)
        f32x4 acc[4];
        #pragma unroll
        for (int g = 0; g < 4; ++g) {
            #pragma unroll
            for (int r = 0; r < 4; ++r)
                acc[g][r] = xs[t][q * 4 + r] * wih[g] + bias[g];
        }

        // gates += h @ W_hh^T ; g-outer so gate 0 finishes first
        #pragma unroll
        for (int g = 0; g < 4; ++g) {
            #pragma unroll
            for (int kc = 0; kc < 4; ++kc)
                acc[g] = __builtin_amdgcn_mfma_f32_16x16x32_f16(af[kc], wf[g][kc], acc[g], 0, 0, 0);
        }

        // elementwise on this wave's 2 rows only (pair wave handles the other 2)
        {
            const int r  = rbase;
            const int b  = q * 4 + r;
            float ig = fsig(acc[0][r]);
            float fg = fsig(acc[1][r]);
            float gg = ftanh(acc[2][r]);
            float og = fsig(acc[3][r]);
            float cn = fg * c0 + ig * gg;
            c0 = cn;
            hbuf[wb][b][jcol] = (_Float16)(og * ftanh(cn));
        }
        {
            const int r  = rbase + 1;
            const int b  = q * 4 + r;
            float ig = fsig(acc[0][r]);
            float fg = fsig(acc[1][r]);
            float gg = ftanh(acc[2][r]);
            float og = fsig(acc[3][r]);
            float cn = fg * c1 + ig * gg;
            c1 = cn;
            hbuf[wb][b][jcol] = (_Float16)(og * ftanh(cn));
        }
        __syncthreads();
    }

    // ---- epilogue: out[b] = fc_b + sum_j fc_W[j] * hT[b][j] (hT in hbuf[0]) ----
    if (tid < 256) {
        const int b    = tid >> 4;
        const int part = tid & 15;
        const _Float16* hrow = &hbuf[0][b][0];
        float s = 0.0f;
        #pragma unroll
        for (int i = 0; i < 8; ++i) {
            const int j = part * 8 + i;
            s += fc_W[j] * (float)hrow[j];
        }
        s += __shfl_xor(s, 8, 16);
        s += __shfl_xor(s, 4, 16);
        s += __shfl_xor(s, 2, 16);
        s += __shfl_xor(s, 1, 16);
        if (part == 0)
            out[blockIdx.x * MB + b] = s + fc_b[0];
    }
}

extern "C" void kernel_launch(void* const* d_in, const int* in_sizes, int n_in,
                              void* d_out, int out_size, void* d_ws, size_t ws_size,
                              hipStream_t stream)
{
    const float* x    = (const float*)d_in[0];
    const float* W_ih = (const float*)d_in[1];
    const float* W_hh = (const float*)d_in[2];
    const float* b_ih = (const float*)d_in[3];
    const float* b_hh = (const float*)d_in[4];
    const float* fc_W = (const float*)d_in[5];
    const float* fc_b = (const float*)d_in[6];
    float* out = (float*)d_out;

    const int B = in_sizes[0] / H;         // 4096 chunks
    dim3 grid(B / MB);                     // 256 blocks -> 1 per CU
    dim3 block(BLOCK);                     // 16 waves -> 4 per SIMD
    hipLaunchKernelGGL(lstm_fused_kernel, grid, block, 0, stream,
                       x, W_ih, W_hh, b_ih, b_hh, fc_W, fc_b, out);
}

// Round 3
// 171.029 us; speedup vs baseline: 1.4509x; 1.4509x over previous
//
#include <hip/hip_runtime.h>

// LSTM_WP: B=4096 batch-1 LSTMs, T=H=128, input_size=1, fused MFMA-f16 recurrence.
// Round 3: root-cause fix. Rounds 1-2 showed FETCH_SIZE ~2.1 GB + VGPR_Count 72:
// the compiler rematerialized the 64-VGPR W_hh fragment array, re-loading 256 KB
// of f32 weights from L2/L3 EVERY step and re-converting to f16 (~320 VALU
// cyc/wave/step). Fix: (1) prep kernel pre-converts W_hh to f16 in fragment-
// contiguous layout in d_ws; (2) empty inline-asm "+v" pins wf in registers;
// (3) kc-outer g-inner MFMA (independent acc chains, no issue stalls);
// (4) next-step preact init computed in the MFMA shadow; (5) fused-rcp gate
// math (7 trans/gate-set instead of 10); (6) conflict-free xs[T+1][20] + b128.

#define H   128
#define T   128
#define MB  16          // batches per block
#define BLOCK 512
#define HSTRIDE 136     // f16 per h row: 272 B = 17*16 -> b128-aligned, 2-way banks (free)
#define XSTRIDE 20      // f32 per xs row: 80 B, 16B-aligned b128 reads, conflict-free

typedef _Float16 f16x8 __attribute__((ext_vector_type(8)));
typedef float    f32x4 __attribute__((ext_vector_type(4)));

// ---------------- prep: W_hh f32 [512][128] -> f16 fragment-contiguous ----------------
// layout: idx(ct,g,kc,q,l15) = (((ct*4+g)*4+kc)*4+q)*16+l15, 8 f16 each (16 B).
// main-kernel load for (g,kc) at fixed ct: lane(q*16+l15) reads idx*16B -> lane-contiguous.
__global__ void prep_whh_kernel(const float* __restrict__ W_hh, _Float16* __restrict__ wfrag)
{
    int idx = blockIdx.x * blockDim.x + threadIdx.x;     // 0..8191
    int l15 =  idx        & 15;
    int q   = (idx >> 4)  & 3;
    int kc  = (idx >> 6)  & 3;
    int g   = (idx >> 8)  & 3;
    int ct  = (idx >> 10) & 7;
    int n  = g * H + ct * 16 + l15;                      // gate row in [0,512)
    int k0 = kc * 32 + q * 8;
    const float* src = W_hh + (size_t)n * H + k0;
    f16x8 f;
    #pragma unroll
    for (int i = 0; i < 8; ++i) f[i] = (_Float16)src[i];
    *(f16x8*)(wfrag + (size_t)idx * 8) = f;
}

__device__ __forceinline__ float frcp(float v) { return __builtin_amdgcn_rcpf(v); }

__launch_bounds__(BLOCK, 2)
__global__ void lstm_fused_kernel(const float* __restrict__ x,
                                  const float* __restrict__ W_ih,
                                  const _Float16* __restrict__ wfrag,
                                  const float* __restrict__ b_ih,
                                  const float* __restrict__ b_hh,
                                  const float* __restrict__ fc_W,
                                  const float* __restrict__ fc_b,
                                  float* __restrict__ out)
{
    __shared__ __align__(16) float xs[T + 1][XSTRIDE];           // +1 row: harmless garbage read at t=T-1 prefetch
    __shared__ __align__(16) _Float16 hbuf[2][MB][HSTRIDE];      // 8.5 KB h double-buffer

    const int tid  = threadIdx.x;
    const int wave = tid >> 6;          // column tile 0..7
    const int lane = tid & 63;
    const int l15  = lane & 15;
    const int q    = lane >> 4;         // 0..3
    const int jcol = wave * 16 + l15;   // hidden column 0..127

    // ---- stage x: [b][t] global -> xs[t][b] (coalesced reads; one-time, conflicts ok) ----
    {
        const int t0 = tid & 127;
        const int b0 = (tid >> 7) * 4;  // 0,4,8,12
        const float* xb = x + (size_t)blockIdx.x * (MB * T);
        #pragma unroll
        for (int bb = 0; bb < 4; ++bb)
            xs[t0][b0 + bb] = xb[(b0 + bb) * T + t0];
    }
    for (int i = tid; i < MB * HSTRIDE; i += BLOCK)              // h0 = 0
        (&hbuf[0][0][0])[i] = (_Float16)0.0f;

    // ---- load pre-converted W_hh fragments (f16, lane-coalesced 16 B each) ----
    f16x8 wf[4][4];                     // [gate][kc], 64 VGPRs
    {
        const _Float16* wbase = wfrag + (size_t)wave * (4 * 4 * 4 * 16 * 8);
        #pragma unroll
        for (int g = 0; g < 4; ++g)
            #pragma unroll
            for (int kc = 0; kc < 4; ++kc)
                wf[g][kc] = *(const f16x8*)(wbase + ((((g * 4 + kc) * 4 + q) * 16 + l15) * 8));
        // pin in registers: opaque to the compiler -> no per-step rematerialization
        #pragma unroll
        for (int g = 0; g < 4; ++g)
            #pragma unroll
            for (int kc = 0; kc < 4; ++kc)
                asm volatile("" : "+v"(wf[g][kc]));
    }

    float wih[4], bias[4];
    #pragma unroll
    for (int g = 0; g < 4; ++g) {
        const int n = g * H + jcol;
        wih[g]  = W_ih[n];
        bias[g] = b_ih[n] + b_hh[n];
    }

    float c0[4] = {0.f, 0.f, 0.f, 0.f};

    __syncthreads();

    // preact init for t=0 (x_0*W_ih + b_ih + b_hh), rows b = q*4+r
    f32x4 initv[4];
    {
        float4 xl = *(const float4*)&xs[0][q * 4];
        #pragma unroll
        for (int g = 0; g < 4; ++g) {
            initv[g][0] = fmaf(xl.x, wih[g], bias[g]);
            initv[g][1] = fmaf(xl.y, wih[g], bias[g]);
            initv[g][2] = fmaf(xl.z, wih[g], bias[g]);
            initv[g][3] = fmaf(xl.w, wih[g], bias[g]);
        }
    }

    for (int t = 0; t < T; ++t) {
        const int rb = t & 1;
        const int wb = rb ^ 1;

        // A-fragments: m(batch)=l15, k = kc*32 + q*8 + i
        f16x8 af[4];
        #pragma unroll
        for (int kc = 0; kc < 4; ++kc)
            af[kc] = *(const f16x8*)&hbuf[rb][l15][kc * 32 + q * 8];

        // gates = init + h @ W_hh^T; kc-outer g-inner -> 4 independent acc chains
        f32x4 acc[4];
        #pragma unroll
        for (int g = 0; g < 4; ++g)
            acc[g] = __builtin_amdgcn_mfma_f32_16x16x32_f16(af[0], wf[g][0], initv[g], 0, 0, 0);
        #pragma unroll
        for (int kc = 1; kc < 4; ++kc)
            #pragma unroll
            for (int g = 0; g < 4; ++g)
                acc[g] = __builtin_amdgcn_mfma_f32_16x16x32_f16(af[kc], wf[g][kc], acc[g], 0, 0, 0);

        // next step's init: independent of MFMA results -> issues in the MFMA shadow
        {
            float4 xl = *(const float4*)&xs[t + 1][q * 4];
            #pragma unroll
            for (int g = 0; g < 4; ++g) {
                initv[g][0] = fmaf(xl.x, wih[g], bias[g]);
                initv[g][1] = fmaf(xl.y, wih[g], bias[g]);
                initv[g][2] = fmaf(xl.z, wih[g], bias[g]);
                initv[g][3] = fmaf(xl.w, wih[g], bias[g]);
            }
        }

        // fused-rcp elementwise: 5 exp + 2 rcp per gate-set (was 5+5)
        #pragma unroll
        for (int r = 0; r < 4; ++r) {
            const int b = q * 4 + r;
            float ai = acc[0][r], afv = acc[1][r], ag = acc[2][r], ao = acc[3][r];
            float Ei = __expf(-ai);                  // sigmoid_i = 1/(1+Ei)
            float Ef = __expf(-afv);                 // sigmoid_f = 1/(1+Ef)
            float Eg = __expf(2.0f * ag);            // tanh_g = (Eg-1)/(Eg+1)
            float u  = 1.0f + Ei;
            float v  = 1.0f + Ef;
            float w  = 1.0f + Eg;
            float wm = Eg - 1.0f;
            float uw = u * w;
            // c' = c/v + wm/(u*w)  ->  [c*u*w + wm*v] / (v*u*w), ONE rcp
            float cn = fmaf(c0[r], uw, wm * v) * frcp(v * uw);
            c0[r] = cn;
            float Eo = __expf(-ao);                  // sigmoid_o = 1/(1+Eo)
            float Ec = __expf(2.0f * cn);            // tanh(c') = (Ec-1)/(Ec+1)
            float hv = (Ec - 1.0f) * frcp((Ec + 1.0f) * (1.0f + Eo));
            hbuf[wb][b][jcol] = (_Float16)hv;
        }
        __syncthreads();
    }

    // ---- epilogue: out[b] = fc_b + sum_j fc_W[j] * hT[b][j]  (hT in hbuf[0]) ----
    if (tid < 256) {
        const int b    = tid >> 4;
        const int part = tid & 15;
        const _Float16* hrow = &hbuf[0][b][0];
        float s = 0.0f;
        #pragma unroll
        for (int i = 0; i < 8; ++i) {
            const int j = part * 8 + i;
            s += fc_W[j] * (float)hrow[j];
        }
        s += __shfl_xor(s, 8, 16);
        s += __shfl_xor(s, 4, 16);
        s += __shfl_xor(s, 2, 16);
        s += __shfl_xor(s, 1, 16);
        if (part == 0)
            out[blockIdx.x * MB + b] = s + fc_b[0];
    }
}

extern "C" void kernel_launch(void* const* d_in, const int* in_sizes, int n_in,
                              void* d_out, int out_size, void* d_ws, size_t ws_size,
                              hipStream_t stream)
{
    const float* x    = (const float*)d_in[0];
    const float* W_ih = (const float*)d_in[1];
    const float* W_hh = (const float*)d_in[2];
    const float* b_ih = (const float*)d_in[3];
    const float* b_hh = (const float*)d_in[4];
    const float* fc_W = (const float*)d_in[5];
    const float* fc_b = (const float*)d_in[6];
    float* out = (float*)d_out;

    _Float16* wfrag = (_Float16*)d_ws;     // 64K f16 = 128 KB fragment-ordered W_hh

    // one-time (per launch) weight conversion: 8192 lane-frags
    hipLaunchKernelGGL(prep_whh_kernel, dim3(32), dim3(256), 0, stream, W_hh, wfrag);

    const int B = in_sizes[0] / H;         // 4096 chunks
    dim3 grid(B / MB);                     // 256 blocks -> 1 per CU
    dim3 block(BLOCK);                     // 8 waves -> 2 per SIMD
    hipLaunchKernelGGL(lstm_fused_kernel, grid, block, 0, stream,
                       x, W_ih, wfrag, b_ih, b_hh, fc_W, fc_b, out);
}